// Round 8
// baseline (462.287 us; speedup 1.0000x reference)
//
#include <hip/hip_runtime.h>
#include <hip/hip_fp16.h>

// Problem constants (fixed by the reference)
#define NN 50000      // nodes
#define EE 800000     // edges
#define FF 64         // F_IN = F_OUT
#define PP 8          // periods
#define NPAD 50048    // padded rows (multiple of 128, >= max GEMM tile row)
#define ELLW 64       // ELL slots per node (in-deg ~ Poisson(16); P(>64) ~ 1e-13)

typedef _Float16 half8 __attribute__((ext_vector_type(8)));
typedef _Float16 half4 __attribute__((ext_vector_type(4)));
typedef float floatx4 __attribute__((ext_vector_type(4)));

static constexpr size_t al512(size_t x) { return (x + 511) & ~size_t(511); }
static constexpr size_t OFF_DEG  = 0;                                  // float[NN]
static constexpr size_t OFF_CNT  = al512(OFF_DEG  + (size_t)NN*4);     // int[NN]
static constexpr size_t OFF_DIS  = al512(OFF_CNT  + (size_t)NN*4);     // float[NN]
static constexpr size_t OFF_ELL  = al512(OFF_DIS  + (size_t)NN*4);     // int2[NN*ELLW]
static constexpr size_t OFF_BIAS = al512(OFF_ELL  + (size_t)NN*ELLW*8);// float[192]
static constexpr size_t OFF_WC2  = al512(OFF_BIAS + 192*4);            // float[64]
static constexpr size_t OFF_WFRG = al512(OFF_WC2  + 64*4);             // half[24576]
static constexpr size_t OFF_XB   = al512(OFF_WFRG + (size_t)24576*2);  // half[NPAD*512]
static constexpr size_t OFF_TB   = al512(OFF_XB   + (size_t)NPAD*512*2); // half[NPAD*512]

// ---- K1a: deg pass ONLY: 800K fire-and-forget f32 atomics ------------------
// Mechanism probe (R7: line-padding null; R5: MLP null; R6: overlap null).
// If device atomics are service-rate-limited (~17 G/s flat): ~44 us.
// If the per-edge RETURN dependency is the stall: this collapses to ~15 us.
__global__ void k_deg(const int* __restrict__ src, const float* __restrict__ ew,
                      float* __restrict__ deg) {
    int e = blockIdx.x * 256 + threadIdx.x;     // EE % 256 == 0: no tail
    atomicAdd(deg + src[e], ew[e]);
}

// ---- K1b: cnt slot-claim + ELL fill (return atomics) -----------------------
__global__ void k_cnt(const int* __restrict__ src, const int* __restrict__ dst,
                      const float* __restrict__ ew,
                      int* __restrict__ cnt, int2* __restrict__ ell) {
    int e = blockIdx.x * 256 + threadIdx.x;
    int s = src[e], d = dst[e];
    float w = ew[e];
    int pos = atomicAdd(cnt + d, 1);
    if (pos < ELLW) {
        int2 pr; pr.x = s; pr.y = __float_as_int(w);
        ell[(size_t)d * ELLW + pos] = pr;
    }
}

// ---- K1c: transpose+cvt X (N,64,8) f32 -> XB[n][p][f] f16 ------------------
__global__ void k_xpose(const float* __restrict__ X, _Float16* __restrict__ XB) {
    __shared__ _Float16 tile[4][512];
    int wid = threadIdx.x >> 6, lane = threadIdx.x & 63;
    int n = blockIdx.x * 4 + wid;               // NN = 12500*4: no tail
    const float4* xp = (const float4*)(X + (size_t)n * 512 + lane * 8);
    float4 a = xp[0], c = xp[1];
    float v[8] = {a.x, a.y, a.z, a.w, c.x, c.y, c.z, c.w};
#pragma unroll
    for (int p = 0; p < PP; ++p)                // [p][f] layout, f = lane
        tile[wid][p * 64 + lane] = (_Float16)v[p];
    half8 vv = *(const half8*)&tile[wid][lane * 8];
    *(half8*)(XB + (size_t)n * 512 + lane * 8) = vv;
}

// ---- K2: weight prep: Wfrag pack + biases + dis (fused) --------------------
// Wfrag[((ks*12+ct)*64 + lane)*8 + j] = W[k = ks*32 + (lane>>4)*8 + j][c = ct*16 + (lane&15)]
__global__ void k_prep(const float* __restrict__ Wx0, const float* __restrict__ Wx1,
                       const float* __restrict__ bx, const float* __restrict__ bh,
                       const float* __restrict__ wc, const float* __restrict__ bg,
                       const float* __restrict__ deg,
                       _Float16* __restrict__ Wfrag, float* __restrict__ biasv,
                       float* __restrict__ wc2, float* __restrict__ dis) {
    int t = blockIdx.x * 256 + threadIdx.x;
    const int gmap[3] = {0, 2, 3};
    if (t < NN) {  // fused dis
        float dg = deg[t];
        dis[t] = dg > 0.f ? rsqrtf(fmaxf(dg, 1e-12f)) : 0.f;
    }
    if (t < 24576) {
        int j8 = t & 7;
        int lane = (t >> 3) & 63;
        int rem = t >> 9;           // [0,48)
        int ct = rem % 12;
        int ks = rem / 12;
        int k = ks * 32 + (lane >> 4) * 8 + j8;
        int gp = ct >> 2;
        int g = gmap[gp];
        int j64 = (ct & 3) * 16 + (lane & 15);
        float val = (k < 64) ? Wx0[((size_t)g * 64 + k) * 64 + j64]
                             : Wx1[((size_t)g * 64 + (k - 64)) * 64 + j64];
        Wfrag[t] = (_Float16)val;
    }
    if (t < 192) {
        int gp = t / 64, j = t % 64;
        int g = gmap[gp];
        biasv[t] = bx[g * 64 + j] + bh[g * 64 + j] + bg[g * 64 + j];
    }
    if (t < 64) wc2[t] = wc[2 * 64 + t];
}

// ---- K4: SpMM gather from ELL, feature-half split + node-range dispatch ----
// Block b: half = b&1, node = n_base + (b>>1)*4 + wid. Launched 2x (halves)
// for profile visibility. Descriptor preamble folds dis[src]*ew (dis 200 KB,
// L2-hot; hides under descriptor load). (src, w) broadcast to SGPRs via
// readlane -> saddr-form row gathers, 16 in flight.
__global__ void k_spmm(const _Float16* __restrict__ XB, const int* __restrict__ cnt,
                       const float* __restrict__ dis, const int2* __restrict__ ell,
                       _Float16* __restrict__ TB, int n_base, int n_end) {
    int wid = threadIdx.x >> 6, lane = threadIdx.x & 63;
    int b = blockIdx.x;
    int half = b & 1;
    int n = n_base + (b >> 1) * 4 + wid;
    if (n >= n_end) return;
    float acc[4] = {0.f, 0.f, 0.f, 0.f};
    int cn = min(cnt[n], ELLW);
    float dn = dis[n];
    const int foff = half * 256 + lane * 4;     // f16 units within a row
    if (cn > 0) {
        const int2* __restrict__ row = ell + (size_t)n * ELLW;
        // lane e holds descriptor e (clamped); weight 0 for padded lanes
        int2 ed = row[min(lane, cn - 1)];
        float wl = (lane < cn) ? dis[ed.x] * __int_as_float(ed.y) : 0.f;
        int wli = __float_as_int(wl);
        for (int base = 0; base < cn; base += 16) {
            half4 r[16];
            float wk[16];
#pragma unroll
            for (int u = 0; u < 16; ++u) {
                int srck = __builtin_amdgcn_readlane(ed.x, base + u);   // SGPR
                wk[u] = __int_as_float(__builtin_amdgcn_readlane(wli, base + u));
                r[u] = *(const half4*)(XB + (size_t)srck * 512 + foff);
            }
#pragma unroll
            for (int u = 0; u < 16; ++u) {
#pragma unroll
                for (int j = 0; j < 4; ++j) acc[j] += wk[u] * (float)r[u][j];
            }
        }
    }
    half4 st;
#pragma unroll
    for (int j = 0; j < 4; ++j) st[j] = (_Float16)(-dn * acc[j]);
    *(half4*)(TB + (size_t)n * 512 + foff) = st;
}

__device__ __forceinline__ float fast_rcp(float x) { return __builtin_amdgcn_rcpf(x); }
__device__ __forceinline__ float sigmoidf_fast(float x) {
    return fast_rcp(1.f + __expf(-x));          // v_exp + v_rcp, no slow division
}
__device__ __forceinline__ float tanhf_fast(float x) {
    return 1.f - 2.f * fast_rcp(1.f + __expf(2.f * x));
}

// ---- K5: MFMA GEMM: no LDS, 1-wave blocks (32 rows each) -------------------
// grid = NPAD/32 = 1564 blocks (~6.1/CU, no barriers). B fragments stream
// straight from Wfrag (48 KB, L2-hot). Unchanged; this round's split of the
// other kernels finally makes its duration visible in top-5 if > ~45 us.
__global__ __launch_bounds__(64) void k_gemm(const _Float16* __restrict__ XB,
                                             const _Float16* __restrict__ TB,
                                             const _Float16* __restrict__ Wfrag,
                                             const float* __restrict__ biasv,
                                             const float* __restrict__ wc2,
                                             float* __restrict__ out) {
    const int lane = threadIdx.x & 63;
    const half8* __restrict__ Wg8 = (const half8*)Wfrag;

    const int n0 = blockIdx.x * 32;
    const int jj = lane & 15, quad = lane >> 4;

    float bi[4], bc[4], bo[4], wcv[4];
#pragma unroll
    for (int c4 = 0; c4 < 4; ++c4) {
        int j = c4 * 16 + jj;
        bi[c4] = biasv[j];
        bc[c4] = biasv[64 + j];
        bo[c4] = biasv[128 + j];
        wcv[c4] = wc2[j];
    }

    const _Float16* __restrict__ x0 = XB + (size_t)(n0 + jj) * 512;
    const _Float16* __restrict__ x1 = XB + (size_t)(n0 + 16 + jj) * 512;
    const _Float16* __restrict__ t0 = TB + (size_t)(n0 + jj) * 512;
    const _Float16* __restrict__ t1 = TB + (size_t)(n0 + 16 + jj) * 512;

    floatx4 outacc[2][4];
#pragma unroll
    for (int r = 0; r < 2; ++r)
#pragma unroll
        for (int c4 = 0; c4 < 4; ++c4) outacc[r][c4] = (floatx4){0.f, 0.f, 0.f, 0.f};

#pragma unroll 1
    for (int p = 0; p < PP; ++p) {
        const int o = p * 64 + quad * 8;
        // A fragments for this period: k = ks*32 + quad*8 + j
        half8 a00 = *(const half8*)(x0 + o);
        half8 a01 = *(const half8*)(x0 + o + 32);
        half8 a02 = *(const half8*)(t0 + o);
        half8 a03 = *(const half8*)(t0 + o + 32);
        half8 a10 = *(const half8*)(x1 + o);
        half8 a11 = *(const half8*)(x1 + o + 32);
        half8 a12 = *(const half8*)(t1 + o);
        half8 a13 = *(const half8*)(t1 + o + 32);
#pragma unroll
        for (int c4 = 0; c4 < 4; ++c4) {
            floatx4 ai0 = {0.f,0.f,0.f,0.f}, ac0 = {0.f,0.f,0.f,0.f}, ao0 = {0.f,0.f,0.f,0.f};
            floatx4 ai1 = {0.f,0.f,0.f,0.f}, ac1 = {0.f,0.f,0.f,0.f}, ao1 = {0.f,0.f,0.f,0.f};
#pragma unroll
            for (int ks = 0; ks < 4; ++ks) {
                half8 bfi = Wg8[(ks * 12 + c4) * 64 + lane];
                half8 bfc = Wg8[(ks * 12 + 4 + c4) * 64 + lane];
                half8 bfo = Wg8[(ks * 12 + 8 + c4) * 64 + lane];
                half8 a0 = (ks == 0) ? a00 : (ks == 1) ? a01 : (ks == 2) ? a02 : a03;
                half8 a1 = (ks == 0) ? a10 : (ks == 1) ? a11 : (ks == 2) ? a12 : a13;
                ai0 = __builtin_amdgcn_mfma_f32_16x16x32_f16(a0, bfi, ai0, 0, 0, 0);
                ai1 = __builtin_amdgcn_mfma_f32_16x16x32_f16(a1, bfi, ai1, 0, 0, 0);
                ac0 = __builtin_amdgcn_mfma_f32_16x16x32_f16(a0, bfc, ac0, 0, 0, 0);
                ac1 = __builtin_amdgcn_mfma_f32_16x16x32_f16(a1, bfc, ac1, 0, 0, 0);
                ao0 = __builtin_amdgcn_mfma_f32_16x16x32_f16(a0, bfo, ao0, 0, 0, 0);
                ao1 = __builtin_amdgcn_mfma_f32_16x16x32_f16(a1, bfo, ao1, 0, 0, 0);
            }
            // fused epilogue: I=sig(ai); T=tanh(ac); Cn=I*T; O=sig(ao+wc2*Cn)
#pragma unroll
            for (int rr = 0; rr < 4; ++rr) {
                float I0 = sigmoidf_fast(ai0[rr] + bi[c4]);
                float T0 = tanhf_fast(ac0[rr] + bc[c4]);
                float Cn0 = I0 * T0;
                float O0 = sigmoidf_fast(ao0[rr] + bo[c4] + wcv[c4] * Cn0);
                outacc[0][c4][rr] += O0 * tanhf_fast(Cn0);
                float I1 = sigmoidf_fast(ai1[rr] + bi[c4]);
                float T1 = tanhf_fast(ac1[rr] + bc[c4]);
                float Cn1 = I1 * T1;
                float O1 = sigmoidf_fast(ao1[rr] + bo[c4] + wcv[c4] * Cn1);
                outacc[1][c4][rr] += O1 * tanhf_fast(Cn1);
            }
        }
    }
    // store: row n = n0 + r*16 + quad*4 + rr, col = c4*16 + jj
#pragma unroll
    for (int r = 0; r < 2; ++r)
#pragma unroll
        for (int c4 = 0; c4 < 4; ++c4)
#pragma unroll
            for (int rr = 0; rr < 4; ++rr) {
                int n = n0 + r * 16 + quad * 4 + rr;
                if (n < NN) out[(size_t)n * 64 + c4 * 16 + jj] = outacc[r][c4][rr];
            }
}

extern "C" void kernel_launch(void* const* d_in, const int* in_sizes, int n_in,
                              void* d_out, int out_size, void* d_ws, size_t ws_size,
                              hipStream_t stream) {
    const float* X   = (const float*)d_in[0];
    const int*   ei  = (const int*)d_in[1];
    const float* ew  = (const float*)d_in[2];
    const float* Wx0 = (const float*)d_in[3];
    const float* Wx1 = (const float*)d_in[4];
    const float* bx  = (const float*)d_in[5];
    // d_in[6], d_in[7] (Wh0, Wh1) are dead: H=0
    const float* bh  = (const float*)d_in[8];
    const float* wc  = (const float*)d_in[9];
    const float* bg  = (const float*)d_in[10];
    float* out = (float*)d_out;

    const int* src = ei;
    const int* dst = ei + EE;

    char* ws = (char*)d_ws;
    float* deg     = (float*)(ws + OFF_DEG);
    int*   cnt     = (int*)(ws + OFF_CNT);
    float* dis     = (float*)(ws + OFF_DIS);
    int2*  ell     = (int2*)(ws + OFF_ELL);
    float* biasv   = (float*)(ws + OFF_BIAS);
    float* wc2     = (float*)(ws + OFF_WC2);
    _Float16* Wfrag = (_Float16*)(ws + OFF_WFRG);
    _Float16* XB    = (_Float16*)(ws + OFF_XB);
    _Float16* TB    = (_Float16*)(ws + OFF_TB);

    // zero deg + cnt (contiguous region at front of ws, ends at OFF_DIS)
    hipMemsetAsync(ws, 0, OFF_DIS, stream);

    k_deg<<<EE / 256, 256, 0, stream>>>(src, ew, deg);
    k_cnt<<<EE / 256, 256, 0, stream>>>(src, dst, ew, cnt, ell);
    k_xpose<<<NN / 4, 256, 0, stream>>>(X, XB);
    k_prep<<<196, 256, 0, stream>>>(Wx0, Wx1, bx, bh, wc, bg, deg, Wfrag, biasv, wc2, dis);
    // spmm split into 2 node-range dispatches (visibility; same total work)
    for (int r = 0; r < 2; ++r) {
        int nb = r * 25000, ne = min(NN, nb + 25000);
        k_spmm<<<2 * ((ne - nb + 3) / 4), 256, 0, stream>>>(XB, cnt, dis, ell, TB, nb, ne);
    }
    k_gemm<<<NPAD / 32, 64, 0, stream>>>(XB, TB, Wfrag, biasv, wc2, out);
}

// Round 9
// 427.292 us; speedup vs baseline: 1.0819x; 1.0819x over previous
//
#include <hip/hip_runtime.h>
#include <hip/hip_fp16.h>

// Problem constants (fixed by the reference)
#define NN 50000      // nodes
#define EE 800000     // edges
#define FF 64         // F_IN = F_OUT
#define PP 8          // periods
#define NPAD 50048    // padded rows (multiple of 128, >= max GEMM tile row)
#define ELLW 64       // ELL slots per node (in-deg ~ Poisson(16); P(>64) ~ 1e-13)
#define NB_BUILD 3125 // EE/256 build blocks in the fused k_bx

typedef _Float16 half8 __attribute__((ext_vector_type(8)));
typedef _Float16 half4 __attribute__((ext_vector_type(4)));
typedef float floatx4 __attribute__((ext_vector_type(4)));

static constexpr size_t al512(size_t x) { return (x + 511) & ~size_t(511); }
static constexpr size_t OFF_DEG  = 0;                                  // float[NN]
static constexpr size_t OFF_CNT  = al512(OFF_DEG  + (size_t)NN*4);     // int[NN]
static constexpr size_t OFF_DIS  = al512(OFF_CNT  + (size_t)NN*4);     // float[NN]
static constexpr size_t OFF_ELL  = al512(OFF_DIS  + (size_t)NN*4);     // int2[NN*ELLW]
static constexpr size_t OFF_BIAS = al512(OFF_ELL  + (size_t)NN*ELLW*8);// float[192]
static constexpr size_t OFF_WC2  = al512(OFF_BIAS + 192*4);            // float[64]
static constexpr size_t OFF_WFRG = al512(OFF_WC2  + 64*4);             // half[24576]
static constexpr size_t OFF_XB   = al512(OFF_WFRG + (size_t)24576*2);  // half[NPAD*512]
static constexpr size_t OFF_TB   = al512(OFF_XB   + (size_t)NPAD*512*2); // half[NPAD*512]

// ---- K1: fused build + xpose (block-specialized; R6's measured-best form) --
// R8 lesson: splitting into 3 kernels cost +22 us (sum-of-parts, again).
__global__ void k_bx(const int* __restrict__ src, const int* __restrict__ dst,
                     const float* __restrict__ ew,
                     float* __restrict__ deg, int* __restrict__ cnt,
                     int2* __restrict__ ell,
                     const float* __restrict__ X, _Float16* __restrict__ XB) {
    __shared__ _Float16 tile[4][512];
    int b = blockIdx.x;
    if (b < NB_BUILD) {
        int e = b * 256 + threadIdx.x;          // EE = NB_BUILD*256: no tail
        int s = src[e], d = dst[e];
        float w = ew[e];
        atomicAdd(deg + s, w);                  // fire-and-forget
        int pos = atomicAdd(cnt + d, 1);        // slot claim
        if (pos < ELLW) {
            int2 pr; pr.x = s; pr.y = __float_as_int(w);
            ell[(size_t)d * ELLW + pos] = pr;
        }
    } else {
        int wid = threadIdx.x >> 6, lane = threadIdx.x & 63;
        int n = (b - NB_BUILD) * 4 + wid;       // NN = 12500*4: no tail
        const float4* xp = (const float4*)(X + (size_t)n * 512 + lane * 8);
        float4 a = xp[0], c = xp[1];
        float v[8] = {a.x, a.y, a.z, a.w, c.x, c.y, c.z, c.w};
#pragma unroll
        for (int p = 0; p < PP; ++p)            // [p][f] layout, f = lane
            tile[wid][p * 64 + lane] = (_Float16)v[p];
        half8 vv = *(const half8*)&tile[wid][lane * 8];
        *(half8*)(XB + (size_t)n * 512 + lane * 8) = vv;
    }
}

// ---- K2: weight prep: Wfrag pack + biases + dis (fused) --------------------
// Wfrag[((ks*12+ct)*64 + lane)*8 + j] = W[k = ks*32 + (lane>>4)*8 + j][c = ct*16 + (lane&15)]
__global__ void k_prep(const float* __restrict__ Wx0, const float* __restrict__ Wx1,
                       const float* __restrict__ bx, const float* __restrict__ bh,
                       const float* __restrict__ wc, const float* __restrict__ bg,
                       const float* __restrict__ deg,
                       _Float16* __restrict__ Wfrag, float* __restrict__ biasv,
                       float* __restrict__ wc2, float* __restrict__ dis) {
    int t = blockIdx.x * 256 + threadIdx.x;
    const int gmap[3] = {0, 2, 3};
    if (t < NN) {  // fused dis
        float dg = deg[t];
        dis[t] = dg > 0.f ? rsqrtf(fmaxf(dg, 1e-12f)) : 0.f;
    }
    if (t < 24576) {
        int j8 = t & 7;
        int lane = (t >> 3) & 63;
        int rem = t >> 9;           // [0,48)
        int ct = rem % 12;
        int ks = rem / 12;
        int k = ks * 32 + (lane >> 4) * 8 + j8;
        int gp = ct >> 2;
        int g = gmap[gp];
        int j64 = (ct & 3) * 16 + (lane & 15);
        float val = (k < 64) ? Wx0[((size_t)g * 64 + k) * 64 + j64]
                             : Wx1[((size_t)g * 64 + (k - 64)) * 64 + j64];
        Wfrag[t] = (_Float16)val;
    }
    if (t < 192) {
        int gp = t / 64, j = t % 64;
        int g = gmap[gp];
        biasv[t] = bx[g * 64 + j] + bh[g * 64 + j] + bg[g * 64 + j];
    }
    if (t < 64) wc2[t] = wc[2 * 64 + t];
}

// ---- K4: SpMM gather from ELL, feature-half split + node-range dispatch ----
__global__ void k_spmm(const _Float16* __restrict__ XB, const int* __restrict__ cnt,
                       const float* __restrict__ dis, const int2* __restrict__ ell,
                       _Float16* __restrict__ TB, int n_base, int n_end) {
    int wid = threadIdx.x >> 6, lane = threadIdx.x & 63;
    int b = blockIdx.x;
    int half = b & 1;
    int n = n_base + (b >> 1) * 4 + wid;
    if (n >= n_end) return;
    float acc[4] = {0.f, 0.f, 0.f, 0.f};
    int cn = min(cnt[n], ELLW);
    float dn = dis[n];
    const int foff = half * 256 + lane * 4;     // f16 units within a row
    if (cn > 0) {
        const int2* __restrict__ row = ell + (size_t)n * ELLW;
        // lane e holds descriptor e (clamped); weight 0 for padded lanes
        int2 ed = row[min(lane, cn - 1)];
        float wl = (lane < cn) ? dis[ed.x] * __int_as_float(ed.y) : 0.f;
        int wli = __float_as_int(wl);
        for (int base = 0; base < cn; base += 16) {
            half4 r[16];
            float wk[16];
#pragma unroll
            for (int u = 0; u < 16; ++u) {
                int srck = __builtin_amdgcn_readlane(ed.x, base + u);   // SGPR
                wk[u] = __int_as_float(__builtin_amdgcn_readlane(wli, base + u));
                r[u] = *(const half4*)(XB + (size_t)srck * 512 + foff);
            }
#pragma unroll
            for (int u = 0; u < 16; ++u) {
#pragma unroll
                for (int j = 0; j < 4; ++j) acc[j] += wk[u] * (float)r[u][j];
            }
        }
    }
    half4 st;
#pragma unroll
    for (int j = 0; j < 4; ++j) st[j] = (_Float16)(-dn * acc[j]);
    *(half4*)(TB + (size_t)n * 512 + foff) = st;
}

__device__ __forceinline__ float fast_rcp(float x) { return __builtin_amdgcn_rcpf(x); }
__device__ __forceinline__ float sigmoidf_fast(float x) {
    return fast_rcp(1.f + __expf(-x));          // v_exp + v_rcp, no slow division
}
__device__ __forceinline__ float tanhf_fast(float x) {
    return 1.f - 2.f * fast_rcp(1.f + __expf(2.f * x));
}

// ---- K5: MFMA GEMM, R9: 2-wave column-split blocks, B register-resident ----
// R8 profile: 85 us, MfmaUtil 9%, Occupancy 7.8%, VGPR 204 -> latency-bound;
// B re-streamed every period through a thrashing L1 (48 KB > 32 KB).
// New: block = 32 rows x 128 thr; wave w owns column-quarters {2w, 2w+1} of
// ALL 3 gates (epilogue self-contained). Its 24 B frags (96 VGPR) load ONCE
// and persist -> per-period loop is 8 A loads + 48 MFMA + epilogue, B traffic
// 8x down, 2x waves (3128), halved per-wave trans work.
__global__ __launch_bounds__(128) void k_gemm(const _Float16* __restrict__ XB,
                                              const _Float16* __restrict__ TB,
                                              const _Float16* __restrict__ Wfrag,
                                              const float* __restrict__ biasv,
                                              const float* __restrict__ wc2,
                                              float* __restrict__ out) {
    const int tid = threadIdx.x;
    const int w = tid >> 6;                 // wave: 0 -> cols 0-31, 1 -> 32-63
    const int lane = tid & 63;
    const half8* __restrict__ Wg8 = (const half8*)Wfrag;

    const int n0 = blockIdx.x * 32;
    const int jj = lane & 15, quad = lane >> 4;

    // B register-resident: [c4local][gate i/c/o][ks]
    half8 Bf[2][3][4];
#pragma unroll
    for (int c4l = 0; c4l < 2; ++c4l)
#pragma unroll
        for (int gp = 0; gp < 3; ++gp)
#pragma unroll
            for (int ks = 0; ks < 4; ++ks)
                Bf[c4l][gp][ks] = Wg8[(ks * 12 + gp * 4 + (w * 2 + c4l)) * 64 + lane];

    float bi[2], bc[2], bo[2], wcv[2];
#pragma unroll
    for (int c4l = 0; c4l < 2; ++c4l) {
        int j = (w * 2 + c4l) * 16 + jj;
        bi[c4l] = biasv[j];
        bc[c4l] = biasv[64 + j];
        bo[c4l] = biasv[128 + j];
        wcv[c4l] = wc2[j];
    }

    const _Float16* __restrict__ x0 = XB + (size_t)(n0 + jj) * 512;
    const _Float16* __restrict__ x1 = XB + (size_t)(n0 + 16 + jj) * 512;
    const _Float16* __restrict__ t0 = TB + (size_t)(n0 + jj) * 512;
    const _Float16* __restrict__ t1 = TB + (size_t)(n0 + 16 + jj) * 512;

    floatx4 outacc[2][2];
#pragma unroll
    for (int r = 0; r < 2; ++r)
#pragma unroll
        for (int c4l = 0; c4l < 2; ++c4l) outacc[r][c4l] = (floatx4){0.f, 0.f, 0.f, 0.f};

#pragma unroll 1
    for (int p = 0; p < PP; ++p) {
        const int o = p * 64 + quad * 8;
        // A fragments for this period: k = ks*32 + quad*8 + j
        half8 a00 = *(const half8*)(x0 + o);
        half8 a01 = *(const half8*)(x0 + o + 32);
        half8 a02 = *(const half8*)(t0 + o);
        half8 a03 = *(const half8*)(t0 + o + 32);
        half8 a10 = *(const half8*)(x1 + o);
        half8 a11 = *(const half8*)(x1 + o + 32);
        half8 a12 = *(const half8*)(t1 + o);
        half8 a13 = *(const half8*)(t1 + o + 32);
#pragma unroll
        for (int c4l = 0; c4l < 2; ++c4l) {
            floatx4 ai0 = {0.f,0.f,0.f,0.f}, ac0 = {0.f,0.f,0.f,0.f}, ao0 = {0.f,0.f,0.f,0.f};
            floatx4 ai1 = {0.f,0.f,0.f,0.f}, ac1 = {0.f,0.f,0.f,0.f}, ao1 = {0.f,0.f,0.f,0.f};
#pragma unroll
            for (int ks = 0; ks < 4; ++ks) {
                half8 a0 = (ks == 0) ? a00 : (ks == 1) ? a01 : (ks == 2) ? a02 : a03;
                half8 a1 = (ks == 0) ? a10 : (ks == 1) ? a11 : (ks == 2) ? a12 : a13;
                ai0 = __builtin_amdgcn_mfma_f32_16x16x32_f16(a0, Bf[c4l][0][ks], ai0, 0, 0, 0);
                ai1 = __builtin_amdgcn_mfma_f32_16x16x32_f16(a1, Bf[c4l][0][ks], ai1, 0, 0, 0);
                ac0 = __builtin_amdgcn_mfma_f32_16x16x32_f16(a0, Bf[c4l][1][ks], ac0, 0, 0, 0);
                ac1 = __builtin_amdgcn_mfma_f32_16x16x32_f16(a1, Bf[c4l][1][ks], ac1, 0, 0, 0);
                ao0 = __builtin_amdgcn_mfma_f32_16x16x32_f16(a0, Bf[c4l][2][ks], ao0, 0, 0, 0);
                ao1 = __builtin_amdgcn_mfma_f32_16x16x32_f16(a1, Bf[c4l][2][ks], ao1, 0, 0, 0);
            }
            // fused epilogue: I=sig(ai); T=tanh(ac); Cn=I*T; O=sig(ao+wc2*Cn)
#pragma unroll
            for (int rr = 0; rr < 4; ++rr) {
                float I0 = sigmoidf_fast(ai0[rr] + bi[c4l]);
                float T0 = tanhf_fast(ac0[rr] + bc[c4l]);
                float Cn0 = I0 * T0;
                float O0 = sigmoidf_fast(ao0[rr] + bo[c4l] + wcv[c4l] * Cn0);
                outacc[0][c4l][rr] += O0 * tanhf_fast(Cn0);
                float I1 = sigmoidf_fast(ai1[rr] + bi[c4l]);
                float T1 = tanhf_fast(ac1[rr] + bc[c4l]);
                float Cn1 = I1 * T1;
                float O1 = sigmoidf_fast(ao1[rr] + bo[c4l] + wcv[c4l] * Cn1);
                outacc[1][c4l][rr] += O1 * tanhf_fast(Cn1);
            }
        }
    }
    // store: row n = n0 + r*16 + quad*4 + rr, col = (w*2+c4l)*16 + jj
#pragma unroll
    for (int r = 0; r < 2; ++r)
#pragma unroll
        for (int c4l = 0; c4l < 2; ++c4l)
#pragma unroll
            for (int rr = 0; rr < 4; ++rr) {
                int n = n0 + r * 16 + quad * 4 + rr;
                if (n < NN) out[(size_t)n * 64 + (w * 2 + c4l) * 16 + jj] = outacc[r][c4l][rr];
            }
}

extern "C" void kernel_launch(void* const* d_in, const int* in_sizes, int n_in,
                              void* d_out, int out_size, void* d_ws, size_t ws_size,
                              hipStream_t stream) {
    const float* X   = (const float*)d_in[0];
    const int*   ei  = (const int*)d_in[1];
    const float* ew  = (const float*)d_in[2];
    const float* Wx0 = (const float*)d_in[3];
    const float* Wx1 = (const float*)d_in[4];
    const float* bx  = (const float*)d_in[5];
    // d_in[6], d_in[7] (Wh0, Wh1) are dead: H=0
    const float* bh  = (const float*)d_in[8];
    const float* wc  = (const float*)d_in[9];
    const float* bg  = (const float*)d_in[10];
    float* out = (float*)d_out;

    const int* src = ei;
    const int* dst = ei + EE;

    char* ws = (char*)d_ws;
    float* deg     = (float*)(ws + OFF_DEG);
    int*   cnt     = (int*)(ws + OFF_CNT);
    float* dis     = (float*)(ws + OFF_DIS);
    int2*  ell     = (int2*)(ws + OFF_ELL);
    float* biasv   = (float*)(ws + OFF_BIAS);
    float* wc2     = (float*)(ws + OFF_WC2);
    _Float16* Wfrag = (_Float16*)(ws + OFF_WFRG);
    _Float16* XB    = (_Float16*)(ws + OFF_XB);
    _Float16* TB    = (_Float16*)(ws + OFF_TB);

    // zero deg + cnt (contiguous region at front of ws, ends at OFF_DIS)
    hipMemsetAsync(ws, 0, OFF_DIS, stream);

    // fused: build (blocks [0, NB_BUILD)) + xpose (blocks [NB_BUILD, +12500))
    k_bx<<<NB_BUILD + NN / 4, 256, 0, stream>>>(src, dst, ew, deg, cnt, ell, X, XB);
    k_prep<<<196, 256, 0, stream>>>(Wx0, Wx1, bx, bh, wc, bg, deg, Wfrag, biasv, wc2, dis);
    // spmm split into 2 node-range dispatches (visibility; same total work)
    for (int r = 0; r < 2; ++r) {
        int nb = r * 25000, ne = min(NN, nb + 25000);
        k_spmm<<<2 * ((ne - nb + 3) / 4), 256, 0, stream>>>(XB, cnt, dis, ell, TB, nb, ne);
    }
    k_gemm<<<NPAD / 32, 128, 0, stream>>>(XB, TB, Wfrag, biasv, wc2, out);
}

// Round 10
// 409.011 us; speedup vs baseline: 1.1303x; 1.0447x over previous
//
#include <hip/hip_runtime.h>
#include <hip/hip_fp16.h>

// Problem constants (fixed by the reference)
#define NN 50000      // nodes
#define EE 800000     // edges
#define FF 64         // F_IN = F_OUT
#define PP 8          // periods
#define NPAD 50048    // padded rows (multiple of 128, >= max GEMM tile row)
#define ELLW 64       // ELL slots per node (in-deg ~ Poisson(16); P(>64) ~ 1e-13)
#define NB_BUILD 1024 // build blocks (grid-stride): ~4 waves/CU so xpose co-runs

typedef _Float16 half8 __attribute__((ext_vector_type(8)));
typedef _Float16 half4 __attribute__((ext_vector_type(4)));
typedef float floatx4 __attribute__((ext_vector_type(4)));

static constexpr size_t al512(size_t x) { return (x + 511) & ~size_t(511); }
static constexpr size_t OFF_DEG  = 0;                                  // float[NN]
static constexpr size_t OFF_CNT  = al512(OFF_DEG  + (size_t)NN*4);     // int[NN]
static constexpr size_t OFF_DIS  = al512(OFF_CNT  + (size_t)NN*4);     // float[NN]
static constexpr size_t OFF_ELL  = al512(OFF_DIS  + (size_t)NN*4);     // int2[NN*ELLW]
static constexpr size_t OFF_BIAS = al512(OFF_ELL  + (size_t)NN*ELLW*8);// float[192]
static constexpr size_t OFF_WC2  = al512(OFF_BIAS + 192*4);            // float[64]
static constexpr size_t OFF_WFRG = al512(OFF_WC2  + 64*4);             // half[24576]
static constexpr size_t OFF_XB   = al512(OFF_WFRG + (size_t)24576*2);  // half[NPAD*512]
static constexpr size_t OFF_TB   = al512(OFF_XB   + (size_t)NPAD*512*2); // half[NPAD*512]

// ---- K1: fused build + xpose, R10 scheduling fix ---------------------------
// R6/R9 lesson: with 3125 build blocks launched first, build's 12.5K waves
// clog the device's wave slots (stalled on the flat ~17 G/s atomic service)
// and xpose only runs in the tail -> SUM of parts. Now build is 1024
// grid-stride blocks (~4 waves/CU, still >>enough outstanding atomics to
// saturate the service point); xpose blocks fill the other ~28 waves/CU and
// stream concurrently under the atomic drain -> MAX of parts.
__global__ void k_bx(const int* __restrict__ src, const int* __restrict__ dst,
                     const float* __restrict__ ew,
                     float* __restrict__ deg, int* __restrict__ cnt,
                     int2* __restrict__ ell,
                     const float* __restrict__ X, _Float16* __restrict__ XB) {
    __shared__ _Float16 tile[4][512];
    int b = blockIdx.x;
    if (b < NB_BUILD) {
        for (int e = b * 256 + threadIdx.x; e < EE; e += NB_BUILD * 256) {
            int s = src[e], d = dst[e];
            float w = ew[e];
            atomicAdd(deg + s, w);              // fire-and-forget
            int pos = atomicAdd(cnt + d, 1);    // slot claim
            if (pos < ELLW) {
                int2 pr; pr.x = s; pr.y = __float_as_int(w);
                ell[(size_t)d * ELLW + pos] = pr;
            }
        }
    } else {
        int wid = threadIdx.x >> 6, lane = threadIdx.x & 63;
        int n = (b - NB_BUILD) * 4 + wid;       // NN = 12500*4: no tail
        const float4* xp = (const float4*)(X + (size_t)n * 512 + lane * 8);
        float4 a = xp[0], c = xp[1];
        float v[8] = {a.x, a.y, a.z, a.w, c.x, c.y, c.z, c.w};
#pragma unroll
        for (int p = 0; p < PP; ++p)            // [p][f] layout, f = lane
            tile[wid][p * 64 + lane] = (_Float16)v[p];
        half8 vv = *(const half8*)&tile[wid][lane * 8];
        *(half8*)(XB + (size_t)n * 512 + lane * 8) = vv;
    }
}

// ---- K2: weight prep: Wfrag pack + biases + dis (fused) --------------------
// Wfrag[((ks*12+ct)*64 + lane)*8 + j] = W[k = ks*32 + (lane>>4)*8 + j][c = ct*16 + (lane&15)]
__global__ void k_prep(const float* __restrict__ Wx0, const float* __restrict__ Wx1,
                       const float* __restrict__ bx, const float* __restrict__ bh,
                       const float* __restrict__ wc, const float* __restrict__ bg,
                       const float* __restrict__ deg,
                       _Float16* __restrict__ Wfrag, float* __restrict__ biasv,
                       float* __restrict__ wc2, float* __restrict__ dis) {
    int t = blockIdx.x * 256 + threadIdx.x;
    const int gmap[3] = {0, 2, 3};
    if (t < NN) {  // fused dis
        float dg = deg[t];
        dis[t] = dg > 0.f ? rsqrtf(fmaxf(dg, 1e-12f)) : 0.f;
    }
    if (t < 24576) {
        int j8 = t & 7;
        int lane = (t >> 3) & 63;
        int rem = t >> 9;           // [0,48)
        int ct = rem % 12;
        int ks = rem / 12;
        int k = ks * 32 + (lane >> 4) * 8 + j8;
        int gp = ct >> 2;
        int g = gmap[gp];
        int j64 = (ct & 3) * 16 + (lane & 15);
        float val = (k < 64) ? Wx0[((size_t)g * 64 + k) * 64 + j64]
                             : Wx1[((size_t)g * 64 + (k - 64)) * 64 + j64];
        Wfrag[t] = (_Float16)val;
    }
    if (t < 192) {
        int gp = t / 64, j = t % 64;
        int g = gmap[gp];
        biasv[t] = bx[g * 64 + j] + bh[g * 64 + j] + bg[g * 64 + j];
    }
    if (t < 64) wc2[t] = wc[2 * 64 + t];
}

// ---- K4: SpMM gather from ELL, feature-half split (single dispatch) --------
// Block b: half = b&1, node = (b>>1)*4 + wid. Descriptors (src, weight)
// broadcast to SGPRs via readlane -> saddr-form row gathers, 16 in flight.
__global__ void k_spmm(const _Float16* __restrict__ XB, const int* __restrict__ cnt,
                       const float* __restrict__ dis, const int2* __restrict__ ell,
                       _Float16* __restrict__ TB) {
    int wid = threadIdx.x >> 6, lane = threadIdx.x & 63;
    int b = blockIdx.x;
    int half = b & 1;
    int n = (b >> 1) * 4 + wid;
    if (n >= NN) return;
    float acc[4] = {0.f, 0.f, 0.f, 0.f};
    int cn = min(cnt[n], ELLW);
    float dn = dis[n];
    const int foff = half * 256 + lane * 4;     // f16 units within a row
    if (cn > 0) {
        const int2* __restrict__ row = ell + (size_t)n * ELLW;
        // lane e holds descriptor e (clamped); weight 0 for padded lanes
        int2 ed = row[min(lane, cn - 1)];
        float wl = (lane < cn) ? dis[ed.x] * __int_as_float(ed.y) : 0.f;
        int wli = __float_as_int(wl);
        for (int base = 0; base < cn; base += 16) {
            half4 r[16];
            float wk[16];
#pragma unroll
            for (int u = 0; u < 16; ++u) {
                int srck = __builtin_amdgcn_readlane(ed.x, base + u);   // SGPR
                wk[u] = __int_as_float(__builtin_amdgcn_readlane(wli, base + u));
                r[u] = *(const half4*)(XB + (size_t)srck * 512 + foff);
            }
#pragma unroll
            for (int u = 0; u < 16; ++u) {
#pragma unroll
                for (int j = 0; j < 4; ++j) acc[j] += wk[u] * (float)r[u][j];
            }
        }
    }
    half4 st;
#pragma unroll
    for (int j = 0; j < 4; ++j) st[j] = (_Float16)(-dn * acc[j]);
    *(half4*)(TB + (size_t)n * 512 + foff) = st;
}

__device__ __forceinline__ float fast_rcp(float x) { return __builtin_amdgcn_rcpf(x); }
__device__ __forceinline__ float sigmoidf_fast(float x) {
    return fast_rcp(1.f + __expf(-x));          // v_exp + v_rcp, no slow division
}
__device__ __forceinline__ float tanhf_fast(float x) {
    return 1.f - 2.f * fast_rcp(1.f + __expf(2.f * x));
}

// ---- K5: MFMA GEMM: 2-wave column-split blocks, B register-resident --------
// R9: 85 -> ~60 us. Block = 32 rows x 128 thr; wave w owns column-quarters
// {2w, 2w+1} of all 3 gates; its 24 B frags (96 VGPR) load once and persist.
__global__ __launch_bounds__(128) void k_gemm(const _Float16* __restrict__ XB,
                                              const _Float16* __restrict__ TB,
                                              const _Float16* __restrict__ Wfrag,
                                              const float* __restrict__ biasv,
                                              const float* __restrict__ wc2,
                                              float* __restrict__ out) {
    const int tid = threadIdx.x;
    const int w = tid >> 6;                 // wave: 0 -> cols 0-31, 1 -> 32-63
    const int lane = tid & 63;
    const half8* __restrict__ Wg8 = (const half8*)Wfrag;

    const int n0 = blockIdx.x * 32;
    const int jj = lane & 15, quad = lane >> 4;

    // B register-resident: [c4local][gate i/c/o][ks]
    half8 Bf[2][3][4];
#pragma unroll
    for (int c4l = 0; c4l < 2; ++c4l)
#pragma unroll
        for (int gp = 0; gp < 3; ++gp)
#pragma unroll
            for (int ks = 0; ks < 4; ++ks)
                Bf[c4l][gp][ks] = Wg8[(ks * 12 + gp * 4 + (w * 2 + c4l)) * 64 + lane];

    float bi[2], bc[2], bo[2], wcv[2];
#pragma unroll
    for (int c4l = 0; c4l < 2; ++c4l) {
        int j = (w * 2 + c4l) * 16 + jj;
        bi[c4l] = biasv[j];
        bc[c4l] = biasv[64 + j];
        bo[c4l] = biasv[128 + j];
        wcv[c4l] = wc2[j];
    }

    const _Float16* __restrict__ x0 = XB + (size_t)(n0 + jj) * 512;
    const _Float16* __restrict__ x1 = XB + (size_t)(n0 + 16 + jj) * 512;
    const _Float16* __restrict__ t0 = TB + (size_t)(n0 + jj) * 512;
    const _Float16* __restrict__ t1 = TB + (size_t)(n0 + 16 + jj) * 512;

    floatx4 outacc[2][2];
#pragma unroll
    for (int r = 0; r < 2; ++r)
#pragma unroll
        for (int c4l = 0; c4l < 2; ++c4l) outacc[r][c4l] = (floatx4){0.f, 0.f, 0.f, 0.f};

#pragma unroll 1
    for (int p = 0; p < PP; ++p) {
        const int o = p * 64 + quad * 8;
        // A fragments for this period: k = ks*32 + quad*8 + j
        half8 a00 = *(const half8*)(x0 + o);
        half8 a01 = *(const half8*)(x0 + o + 32);
        half8 a02 = *(const half8*)(t0 + o);
        half8 a03 = *(const half8*)(t0 + o + 32);
        half8 a10 = *(const half8*)(x1 + o);
        half8 a11 = *(const half8*)(x1 + o + 32);
        half8 a12 = *(const half8*)(t1 + o);
        half8 a13 = *(const half8*)(t1 + o + 32);
#pragma unroll
        for (int c4l = 0; c4l < 2; ++c4l) {
            floatx4 ai0 = {0.f,0.f,0.f,0.f}, ac0 = {0.f,0.f,0.f,0.f}, ao0 = {0.f,0.f,0.f,0.f};
            floatx4 ai1 = {0.f,0.f,0.f,0.f}, ac1 = {0.f,0.f,0.f,0.f}, ao1 = {0.f,0.f,0.f,0.f};
#pragma unroll
            for (int ks = 0; ks < 4; ++ks) {
                half8 a0 = (ks == 0) ? a00 : (ks == 1) ? a01 : (ks == 2) ? a02 : a03;
                half8 a1 = (ks == 0) ? a10 : (ks == 1) ? a11 : (ks == 2) ? a12 : a13;
                ai0 = __builtin_amdgcn_mfma_f32_16x16x32_f16(a0, Bf[c4l][0][ks], ai0, 0, 0, 0);
                ai1 = __builtin_amdgcn_mfma_f32_16x16x32_f16(a1, Bf[c4l][0][ks], ai1, 0, 0, 0);
                ac0 = __builtin_amdgcn_mfma_f32_16x16x32_f16(a0, Bf[c4l][1][ks], ac0, 0, 0, 0);
                ac1 = __builtin_amdgcn_mfma_f32_16x16x32_f16(a1, Bf[c4l][1][ks], ac1, 0, 0, 0);
                ao0 = __builtin_amdgcn_mfma_f32_16x16x32_f16(a0, Bf[c4l][2][ks], ao0, 0, 0, 0);
                ao1 = __builtin_amdgcn_mfma_f32_16x16x32_f16(a1, Bf[c4l][2][ks], ao1, 0, 0, 0);
            }
            // fused epilogue: I=sig(ai); T=tanh(ac); Cn=I*T; O=sig(ao+wc2*Cn)
#pragma unroll
            for (int rr = 0; rr < 4; ++rr) {
                float I0 = sigmoidf_fast(ai0[rr] + bi[c4l]);
                float T0 = tanhf_fast(ac0[rr] + bc[c4l]);
                float Cn0 = I0 * T0;
                float O0 = sigmoidf_fast(ao0[rr] + bo[c4l] + wcv[c4l] * Cn0);
                outacc[0][c4l][rr] += O0 * tanhf_fast(Cn0);
                float I1 = sigmoidf_fast(ai1[rr] + bi[c4l]);
                float T1 = tanhf_fast(ac1[rr] + bc[c4l]);
                float Cn1 = I1 * T1;
                float O1 = sigmoidf_fast(ao1[rr] + bo[c4l] + wcv[c4l] * Cn1);
                outacc[1][c4l][rr] += O1 * tanhf_fast(Cn1);
            }
        }
    }
    // store: row n = n0 + r*16 + quad*4 + rr, col = (w*2+c4l)*16 + jj
#pragma unroll
    for (int r = 0; r < 2; ++r)
#pragma unroll
        for (int c4l = 0; c4l < 2; ++c4l)
#pragma unroll
            for (int rr = 0; rr < 4; ++rr) {
                int n = n0 + r * 16 + quad * 4 + rr;
                if (n < NN) out[(size_t)n * 64 + (w * 2 + c4l) * 16 + jj] = outacc[r][c4l][rr];
            }
}

extern "C" void kernel_launch(void* const* d_in, const int* in_sizes, int n_in,
                              void* d_out, int out_size, void* d_ws, size_t ws_size,
                              hipStream_t stream) {
    const float* X   = (const float*)d_in[0];
    const int*   ei  = (const int*)d_in[1];
    const float* ew  = (const float*)d_in[2];
    const float* Wx0 = (const float*)d_in[3];
    const float* Wx1 = (const float*)d_in[4];
    const float* bx  = (const float*)d_in[5];
    // d_in[6], d_in[7] (Wh0, Wh1) are dead: H=0
    const float* bh  = (const float*)d_in[8];
    const float* wc  = (const float*)d_in[9];
    const float* bg  = (const float*)d_in[10];
    float* out = (float*)d_out;

    const int* src = ei;
    const int* dst = ei + EE;

    char* ws = (char*)d_ws;
    float* deg     = (float*)(ws + OFF_DEG);
    int*   cnt     = (int*)(ws + OFF_CNT);
    float* dis     = (float*)(ws + OFF_DIS);
    int2*  ell     = (int2*)(ws + OFF_ELL);
    float* biasv   = (float*)(ws + OFF_BIAS);
    float* wc2     = (float*)(ws + OFF_WC2);
    _Float16* Wfrag = (_Float16*)(ws + OFF_WFRG);
    _Float16* XB    = (_Float16*)(ws + OFF_XB);
    _Float16* TB    = (_Float16*)(ws + OFF_TB);

    // zero deg + cnt (contiguous region at front of ws, ends at OFF_DIS)
    hipMemsetAsync(ws, 0, OFF_DIS, stream);

    // fused: build (blocks [0, NB_BUILD), grid-stride) + xpose (rest)
    k_bx<<<NB_BUILD + NN / 4, 256, 0, stream>>>(src, dst, ew, deg, cnt, ell, X, XB);
    k_prep<<<196, 256, 0, stream>>>(Wx0, Wx1, bx, bh, wc, bg, deg, Wfrag, biasv, wc2, dis);
    k_spmm<<<2 * (NN / 4), 256, 0, stream>>>(XB, cnt, dis, ell, TB);
    k_gemm<<<NPAD / 32, 128, 0, stream>>>(XB, TB, Wfrag, biasv, wc2, out);
}